// Round 8
// baseline (1776.119 us; speedup 1.0000x reference)
//
#include <hip/hip_runtime.h>
#include <hip/hip_bf16.h>

#define T_   20
#define B_   4
#define NN_  500
#define M_   2000
#define TM_  40000   // T_*M_
#define H_   128
#define G_   512     // 4*H_
#define H2_  64
#define OUT_ 32
#define ECAP 64
#define TG_  (T_ * G_)

typedef unsigned short ushort_t;
typedef unsigned int   uint_t;
typedef _Float16       f16;
typedef f16 f16x2 __attribute__((ext_vector_type(2)));
typedef f16 f16x8 __attribute__((ext_vector_type(8)));
typedef float f32x4 __attribute__((ext_vector_type(4)));

#if defined(__has_builtin)
#  if __has_builtin(__builtin_amdgcn_fdot2)
#    define HAVE_FDOT2 1
#  endif
#endif

__device__ inline float fdot2_(f16x2 a, f16x2 b, float c) {
#ifdef HAVE_FDOT2
    return __builtin_amdgcn_fdot2(a, b, c, false);
#else
    return c + (float)a.x * (float)b.x + (float)a.y * (float)b.y;
#endif
}

__device__ inline float fast_sig(float x) {
    float e = __builtin_amdgcn_exp2f(x * -1.4426950408889634f);
    return __builtin_amdgcn_rcpf(1.f + e);
}
__device__ inline float fast_tanh(float x) {
    float e = __builtin_amdgcn_exp2f(x * 2.8853900817779268f);
    return 1.f - 2.f * __builtin_amdgcn_rcpf(e + 1.f);
}

// raw barrier: no compiler-inserted s_waitcnt vmcnt(0) drain.
// LDS pipe is in-order per CU (validated R3-R7: correct results).
#define BARRAW() asm volatile("s_barrier" ::: "memory")

// quad butterfly add via DPP (VALU pipe, no DS ops).
// 0xB1 = quad_perm [1,0,3,2] (xor1), 0x4E = quad_perm [2,3,0,1] (xor2).
#define DPPADD(v, ctrl)                                                       \
    do {                                                                      \
        int nb_ = __builtin_amdgcn_update_dpp(                                \
            0, __builtin_bit_cast(int, v), (ctrl), 0xF, 0xF, true);           \
        v += __builtin_bit_cast(float, nb_);                                  \
    } while (0)

// ---- K0: detect ego dtype + build mask[t][i] + zero ecnt ---------------
__global__ __launch_bounds__(1024) void k0_mask(const void* __restrict__ ego,
                                                float* __restrict__ mf,
                                                int* __restrict__ ecnt) {
    __shared__ int fl[3];
    int tid = threadIdx.x;
    if (tid < 3) fl[tid] = 0;
    __syncthreads();
    const uint_t* dw = (const uint_t*)ego;
    int a = 0, b = 0, c = 0;
    for (int i = tid; i < 2500; i += 1024) {   // 10 KB <= any dtype's size
        uint_t v = dw[i];
        bool isf32  = (v == 0x3F800000u);
        bool isbf16 = (v == 0x00003F80u) || (v == 0x3F803F80u);
        if (isf32)  a = 1;
        if (isbf16) b = 1;
        if (v > 1u && !isf32 && !isbf16) c = 1;
    }
    if (a) fl[0] = 1;
    if (b) fl[1] = 1;
    if (c) fl[2] = 1;
    __syncthreads();
    int mode;                       // 0=int32, 1=uint8, 2=f32, 3=bf16
    if (fl[1])      mode = 3;
    else if (fl[0]) mode = 2;
    else if (fl[2]) mode = 1;
    else            mode = 0;
    int e = blockIdx.x * 1024 + tid;
    if (e >= TM_) return;
    ecnt[e] = 0;
    int t = e / M_, i = e % M_;
    int bb = i / NN_, n = i % NN_;
    int src = (bb * T_ + t) * NN_ + n;
    bool on;
    if (mode == 0)      on = ((const int*)ego)[src] != 0;
    else if (mode == 1) on = ((const unsigned char*)ego)[src] != 0;
    else if (mode == 2) on = ((const float*)ego)[src] != 0.f;
    else                on = ((const ushort_t*)ego)[src] != 0;
    mf[e] = on ? 1.f : 0.f;
}

// ---- K1: strip-parallel adjacency scan, atomic slot alloc --------------
#define JSTRIP 200
__global__ void k1_scan(const float* __restrict__ adj, const float* __restrict__ mf,
                        int* __restrict__ ecnt, int* __restrict__ edges) {
    __shared__ float ms[JSTRIP];
    int t = blockIdx.y, j0 = blockIdx.z * JSTRIP;
    int i = blockIdx.x * 256 + threadIdx.x;
    for (int idx = threadIdx.x; idx < JSTRIP; idx += 256)
        ms[idx] = mf[t * M_ + j0 + idx];
    __syncthreads();
    if (i >= M_) return;
    if (mf[t * M_ + i] == 0.f) return;          // masked column: no edges
    const float* ap = adj + (size_t)t * M_ * M_ + (size_t)j0 * M_ + i;
    int r = t * M_ + i;
    int* ep = edges + (size_t)r * ECAP;
#pragma unroll 8
    for (int jj = 0; jj < JSTRIP; ++jj) {
        float av = ap[(size_t)jj * M_];
        if (av != 0.f && ms[jj] != 0.f) {
            int pos = atomicAdd(&ecnt[r], 1);
            if (pos < ECAP) ep[pos] = j0 + jj;
        }
    }
}

// ---- K2: dinv from ecnt/mf; Y1 = dinv * (x @ W1) -----------------------
__global__ void k2_y1(const float* __restrict__ pos, const float* __restrict__ W1,
                      const float* __restrict__ mf, const int* __restrict__ ecnt,
                      float* __restrict__ dinv, f16* __restrict__ Y1) {
    int gid = blockIdx.x * 256 + threadIdx.x;    // over TM_*H_
    int r = gid >> 7, h = gid & 127;
    if (r >= TM_) return;
    float mr = mf[r];
    int cnt = ecnt[r];
    float dv = (mr != 0.f) ? __frsqrt_rn((float)(cnt + 1)) : 0.f;
    if (h == 0) dinv[r] = dv;
    float2 xy = ((const float2*)pos)[r];
    float v = xy.x * W1[h] + xy.y * W1[H_ + h];
    Y1[gid] = (f16)(dv * v);
}

// ---- K3: h1 = relu(dinv*(sum_edges Y1 + Y1_self) + b1), f16x2 lanes ----
__global__ __launch_bounds__(64) void k3_agg1(const f16* __restrict__ Y1,
        const float* __restrict__ dinv, const int* __restrict__ ecnt,
        const int* __restrict__ edges, const float* __restrict__ b1,
        f16* __restrict__ h1) {
    int r = blockIdx.x, q = threadIdx.x;   // q: h-pair index 0..63
    int t = r / M_, base = t * M_;
    const uint_t* Yu = (const uint_t*)Y1;
    f16x2 sp = __builtin_bit_cast(f16x2, Yu[(size_t)r * 64 + q]);
    float a0 = (float)sp.x, a1 = (float)sp.y;
    int ec = ecnt[r]; if (ec > ECAP) ec = ECAP;
    const int4* ep4 = (const int4*)(edges + (size_t)r * ECAP);
    for (int e = 0; e < ec; e += 4) {
        int4 ix = ep4[e >> 2];
        int j1 = (e + 1 < ec) ? ix.y : ix.x;
        int j2 = (e + 2 < ec) ? ix.z : ix.x;
        int j3 = (e + 3 < ec) ? ix.w : ix.x;
        uint_t u0 = Yu[(size_t)(base + ix.x) * 64 + q];
        uint_t u1 = Yu[(size_t)(base + j1) * 64 + q];
        uint_t u2 = Yu[(size_t)(base + j2) * 64 + q];
        uint_t u3 = Yu[(size_t)(base + j3) * 64 + q];
        f16x2 p0 = __builtin_bit_cast(f16x2, u0);
        a0 += (float)p0.x; a1 += (float)p0.y;
        if (e + 1 < ec) { f16x2 p = __builtin_bit_cast(f16x2, u1); a0 += (float)p.x; a1 += (float)p.y; }
        if (e + 2 < ec) { f16x2 p = __builtin_bit_cast(f16x2, u2); a0 += (float)p.x; a1 += (float)p.y; }
        if (e + 3 < ec) { f16x2 p = __builtin_bit_cast(f16x2, u3); a0 += (float)p.x; a1 += (float)p.y; }
    }
    float dv = dinv[r];
    float o0 = dv * a0 + b1[2 * q];
    float o1 = dv * a1 + b1[2 * q + 1];
    f16x2 op; op.x = (f16)fmaxf(o0, 0.f); op.y = (f16)fmaxf(o1, 0.f);
    ((uint_t*)h1)[(size_t)r * 64 + q] = __builtin_bit_cast(uint_t, op);
}

// ---- K5: placeholder = (dinv*(sum Y2 + Y2_self) + b2) * m --------------
__global__ __launch_bounds__(64) void k5_agg2(const f16* __restrict__ Y2,
        const float* __restrict__ dinv, const float* __restrict__ mf,
        const int* __restrict__ ecnt, const int* __restrict__ edges,
        const float* __restrict__ b2, f16* __restrict__ ph) {
    int r = blockIdx.x, q = threadIdx.x;
    int t = r / M_, base = t * M_;
    const uint_t* Yu = (const uint_t*)Y2;
    f16x2 sp = __builtin_bit_cast(f16x2, Yu[(size_t)r * 64 + q]);
    float a0 = (float)sp.x, a1 = (float)sp.y;
    int ec = ecnt[r]; if (ec > ECAP) ec = ECAP;
    const int4* ep4 = (const int4*)(edges + (size_t)r * ECAP);
    for (int e = 0; e < ec; e += 4) {
        int4 ix = ep4[e >> 2];
        int j1 = (e + 1 < ec) ? ix.y : ix.x;
        int j2 = (e + 2 < ec) ? ix.z : ix.x;
        int j3 = (e + 3 < ec) ? ix.w : ix.x;
        uint_t u0 = Yu[(size_t)(base + ix.x) * 64 + q];
        uint_t u1 = Yu[(size_t)(base + j1) * 64 + q];
        uint_t u2 = Yu[(size_t)(base + j2) * 64 + q];
        uint_t u3 = Yu[(size_t)(base + j3) * 64 + q];
        f16x2 p0 = __builtin_bit_cast(f16x2, u0);
        a0 += (float)p0.x; a1 += (float)p0.y;
        if (e + 1 < ec) { f16x2 p = __builtin_bit_cast(f16x2, u1); a0 += (float)p.x; a1 += (float)p.y; }
        if (e + 2 < ec) { f16x2 p = __builtin_bit_cast(f16x2, u2); a0 += (float)p.x; a1 += (float)p.y; }
        if (e + 3 < ec) { f16x2 p = __builtin_bit_cast(f16x2, u3); a0 += (float)p.x; a1 += (float)p.y; }
    }
    float dv = dinv[r], mr = mf[r];
    f16x2 op;
    op.x = (f16)((dv * a0 + b2[2 * q]) * mr);
    op.y = (f16)((dv * a1 + b2[2 * q + 1]) * mr);
    ((uint_t*)ph)[(size_t)r * 64 + q] = __builtin_bit_cast(uint_t, op);
}

// ---- MFMA GEMM: [TM_ x 128] f16 @ [128 x Ntot] -> f16 ------------------
// mode=1 stores xg GATE-INTERLEAVED: slot (n&127)*4 + (n>>7).
#define ALD 136   // padded LDS leading dim in f16
__global__ __launch_bounds__(256) void kgemm_mfma(const f16* __restrict__ A,
        const float* __restrict__ Bw, int bTrans, int Ntot, int mode,
        const float* __restrict__ dinv, const float* __restrict__ ba,
        const float* __restrict__ bb, f16* __restrict__ Out) {
    __shared__ f16 As[64 * ALD];
    __shared__ f16 Bs[64 * ALD];
    int m0 = blockIdx.x * 64;
    int n0 = blockIdx.y * 64;
    int tid = threadIdx.x;
#pragma unroll
    for (int u = 0; u < 4; ++u) {
        int idx = u * 256 + tid;
        int row = idx >> 4, seg = idx & 15;
        *(f16x8*)&As[row * ALD + seg * 8] =
            *(const f16x8*)(A + (size_t)(m0 + row) * H_ + seg * 8);
    }
    if (bTrans) {   // Bw [Ntot][128]
#pragma unroll
        for (int u = 0; u < 16; ++u) {
            int idx = u * 256 + tid;
            int n = idx >> 6, k2 = (idx & 63) * 2;
            float2 v = *(const float2*)(Bw + (size_t)(n0 + n) * H_ + k2);
            f16x2 pk; pk.x = (f16)v.x; pk.y = (f16)v.y;
            *(uint_t*)&Bs[n * ALD + k2] = __builtin_bit_cast(uint_t, pk);
        }
    } else {        // Bw [128][Ntot]
#pragma unroll
        for (int u = 0; u < 16; ++u) {
            int idx = u * 256 + tid;
            int n = idx >> 6, k2 = (idx & 63) * 2;
            f16x2 pk;
            pk.x = (f16)Bw[(size_t)k2 * Ntot + n0 + n];
            pk.y = (f16)Bw[(size_t)(k2 + 1) * Ntot + n0 + n];
            *(uint_t*)&Bs[n * ALD + k2] = __builtin_bit_cast(uint_t, pk);
        }
    }
    __syncthreads();
    int w = tid >> 6, lane = tid & 63;
    int col = lane & 15, quad = lane >> 4;
    f32x4 acc[4] = {};
#pragma unroll
    for (int kk = 0; kk < 4; ++kk) {
        f16x8 af = *(const f16x8*)&As[(w * 16 + col) * ALD + kk * 32 + quad * 8];
#pragma unroll
        for (int nt = 0; nt < 4; ++nt) {
            f16x8 bf = *(const f16x8*)&Bs[(nt * 16 + col) * ALD + kk * 32 + quad * 8];
            acc[nt] = __builtin_amdgcn_mfma_f32_16x16x32_f16(af, bf, acc[nt], 0, 0, 0);
        }
    }
    if (mode == 0) {
        float dv[4];
#pragma unroll
        for (int reg = 0; reg < 4; ++reg)
            dv[reg] = dinv[m0 + w * 16 + quad * 4 + reg];
#pragma unroll
        for (int nt = 0; nt < 4; ++nt) {
            int n = n0 + nt * 16 + col;
#pragma unroll
            for (int reg = 0; reg < 4; ++reg) {
                int r = m0 + w * 16 + quad * 4 + reg;
                Out[(size_t)r * Ntot + n] = (f16)(dv[reg] * acc[nt][reg]);
            }
        }
    } else {
#pragma unroll
        for (int nt = 0; nt < 4; ++nt) {
            int n = n0 + nt * 16 + col;
            float bias = ba[n] + bb[n];
            int pos = (n & 127) * 4 + (n >> 7);   // gate-interleaved slot
#pragma unroll
            for (int reg = 0; reg < 4; ++reg) {
                int r = m0 + w * 16 + quad * 4 + reg;
                int t = r / M_, s = r % M_;
                Out[((size_t)s * T_ + t) * G_ + pos] = (f16)(acc[nt][reg] + bias);
            }
        }
    }
}

// ---- K7: 20 LSTM chains; VALU dot2 + DPP quad-reduce, no MFMA ----------
// tid = m*4 + q: quad = h-index m (0..127), lane q = 32-elem k-chunk AND
// gate-type owner. Per lane: 4 gate-partials (16 fdot2 each, independent
// chains) over its k-chunk; x[gate q] added into acc[q] pre-reduction;
// quad butterfly via update_dpp (VALU pipe, no DS) gives every lane all 4
// full sums; redundant-per-quad update; lane q==0 writes h. One raw
// barrier per step; h double-buffered.
__global__ __launch_bounds__(512, 2) void k7_lstm(const float* __restrict__ Whh,
        const f16* __restrict__ xg, f16* __restrict__ lo) {
    __shared__ ushort_t hb2[2][H_];   // double-buffered h (128 f16 each)
    int t = blockIdx.x, tid = threadIdx.x;
    int m = tid >> 2, q = tid & 3;
    // weights: wv[gt][d] = W_hh[gt*128+m][q*32 + 2d .. +1] as f16x2
    f16x2 wv[4][16];
#pragma unroll
    for (int gt = 0; gt < 4; ++gt) {
        const float* wr = Whh + (size_t)(gt * H_ + m) * H_ + q * 32;
#pragma unroll
        for (int d = 0; d < 16; ++d) {
            f16x2 p; p.x = (f16)wr[2 * d]; p.y = (f16)wr[2 * d + 1];
            wv[gt][d] = p;
        }
    }
    if (tid < H_) hb2[0][tid] = 0;
    float cst = 0.f;
    // xg gate-interleaved: ushort index (s*T+t)*512 + m*4 + q
    const ushort_t* xpu = (const ushort_t*)xg + t * G_ + m * 4 + q;
    ushort_t xa[8], xb[8];
#pragma unroll
    for (int k = 0; k < 8; ++k) xa[k] = xpu[(size_t)k * TG_];
    __syncthreads();

#define LSTM_STEP(S, XV)                                                      \
    do {                                                                      \
        const ushort_t* hp = &hb2[(S) & 1][q * 32];                           \
        uint4 u0 = ((const uint4*)hp)[0];                                     \
        uint4 u1 = ((const uint4*)hp)[1];                                     \
        uint4 u2 = ((const uint4*)hp)[2];                                     \
        uint4 u3 = ((const uint4*)hp)[3];                                     \
        uint_t hu[16] = {u0.x, u0.y, u0.z, u0.w, u1.x, u1.y, u1.z, u1.w,      \
                         u2.x, u2.y, u2.z, u2.w, u3.x, u3.y, u3.z, u3.w};     \
        float a0 = 0.f, a1 = 0.f, a2 = 0.f, a3 = 0.f;                         \
        _Pragma("unroll")                                                     \
        for (int d = 0; d < 16; ++d) {                                        \
            f16x2 e = __builtin_bit_cast(f16x2, hu[d]);                       \
            a0 = fdot2_(wv[0][d], e, a0);                                     \
            a1 = fdot2_(wv[1][d], e, a1);                                     \
            a2 = fdot2_(wv[2][d], e, a2);                                     \
            a3 = fdot2_(wv[3][d], e, a3);                                     \
        }                                                                     \
        float xf = (float)__builtin_bit_cast(f16, (ushort_t)(XV));            \
        a0 += (q == 0) ? xf : 0.f;                                            \
        a1 += (q == 1) ? xf : 0.f;                                            \
        a2 += (q == 2) ? xf : 0.f;                                            \
        a3 += (q == 3) ? xf : 0.f;                                            \
        DPPADD(a0, 0xB1); DPPADD(a0, 0x4E);                                   \
        DPPADD(a1, 0xB1); DPPADD(a1, 0x4E);                                   \
        DPPADD(a2, 0xB1); DPPADD(a2, 0x4E);                                   \
        DPPADD(a3, 0xB1); DPPADD(a3, 0x4E);                                   \
        float gi = fast_sig(a0), gf = fast_sig(a1);                           \
        float gg = fast_tanh(a2), go = fast_sig(a3);                          \
        cst = gf * cst + gi * gg;                                             \
        float hv_ = go * fast_tanh(cst);                                      \
        f16 hh = (f16)hv_;                                                    \
        if (q == 0) {                                                         \
            hb2[((S) & 1) ^ 1][m] = __builtin_bit_cast(ushort_t, hh);         \
            lo[((size_t)(S) * T_ + t) * H_ + m] = hh;                         \
        }                                                                     \
        BARRAW();                                                             \
    } while (0)

    for (int c2 = 0; c2 < 125; ++c2) {
        int s0 = c2 * 16;
#pragma unroll
        for (int k = 0; k < 8; ++k) xb[k] = xpu[(size_t)(s0 + 8 + k) * TG_];
#pragma unroll
        for (int k = 0; k < 8; ++k) LSTM_STEP(s0 + k, xa[k]);
        int nbs = (s0 + 16 <= M_ - 8) ? s0 + 16 : M_ - 8;
#pragma unroll
        for (int k = 0; k < 8; ++k) xa[k] = xpu[(size_t)(nbs + k) * TG_];
#pragma unroll
        for (int k = 0; k < 8; ++k) LSTM_STEP(s0 + 8 + k, xb[k]);
    }
#undef LSTM_STEP
}

// ---- K8: fc1(relu)+fc2; weights in VGPRs; stream 4 rows/iter -----------
__global__ __launch_bounds__(256) void k8_fc(const f16* __restrict__ lo,
        const float* __restrict__ w1, const float* __restrict__ fb1,
        const float* __restrict__ w2, const float* __restrict__ fb2,
        float* __restrict__ out) {
    __shared__ uint_t hl[4][H_ / 2];   // 4 rows x 128 f16
    __shared__ float o1f[4][H2_];
    int tid = threadIdx.x;
    int o = tid & 63, rr = tid >> 6;
    f16x2 w1c[64];
#pragma unroll
    for (int d = 0; d < 64; ++d) {
        f16x2 p;
        p.x = (f16)w1[(2 * d) * H2_ + o];
        p.y = (f16)w1[(2 * d + 1) * H2_ + o];
        w1c[d] = p;
    }
    int o2 = o & 31;
    float w2f[64];
#pragma unroll
    for (int d = 0; d < 64; ++d) w2f[d] = w2[d * OUT_ + o2];
    float fb1v = fb1[o], fb2v = fb2[o2];

    for (int r0 = blockIdx.x * 4; r0 < TM_; r0 += 512 * 4) {
        {
            int row = tid >> 6, qq = tid & 63;
            hl[row][qq] = ((const uint_t*)lo)[(size_t)(r0 + row) * 64 + qq];
        }
        __syncthreads();
        float acc = fb1v;
        const uint4* hb = (const uint4*)&hl[rr][0];
#pragma unroll
        for (int d = 0; d < 16; ++d) {
            uint4 hv = hb[d];
            acc = fdot2_(w1c[4 * d + 0], __builtin_bit_cast(f16x2, hv.x), acc);
            acc = fdot2_(w1c[4 * d + 1], __builtin_bit_cast(f16x2, hv.y), acc);
            acc = fdot2_(w1c[4 * d + 2], __builtin_bit_cast(f16x2, hv.z), acc);
            acc = fdot2_(w1c[4 * d + 3], __builtin_bit_cast(f16x2, hv.w), acc);
        }
        o1f[rr][o] = fmaxf(acc, 0.f);
        __syncthreads();
        if (o < OUT_) {
            float a2 = fb2v;
            const float4* ob = (const float4*)&o1f[rr][0];
#pragma unroll
            for (int d = 0; d < 16; ++d) {
                float4 v = ob[d];
                a2 += v.x * w2f[4 * d + 0] + v.y * w2f[4 * d + 1]
                    + v.z * w2f[4 * d + 2] + v.w * w2f[4 * d + 3];
            }
            out[(size_t)(r0 + rr) * OUT_ + o] = a2;
        }
        __syncthreads();
    }
}

extern "C" void kernel_launch(void* const* d_in, const int* in_sizes, int n_in,
                              void* d_out, int out_size, void* d_ws, size_t ws_size,
                              hipStream_t stream) {
    const float* positions = (const float*)d_in[0];
    const float* adjacency = (const float*)d_in[1];
    const void*  ego       = d_in[2];
    const float* W1   = (const float*)d_in[3];
    const float* b1   = (const float*)d_in[4];
    const float* W2   = (const float*)d_in[5];
    const float* b2   = (const float*)d_in[6];
    const float* W_ih = (const float*)d_in[7];
    const float* W_hh = (const float*)d_in[8];
    const float* b_ih = (const float*)d_in[9];
    const float* b_hh = (const float*)d_in[10];
    const float* fc1w = (const float*)d_in[11];
    const float* fc1b = (const float*)d_in[12];
    const float* fc2w = (const float*)d_in[13];
    const float* fc2b = (const float*)d_in[14];
    float* out = (float*)d_out;

    char* p = (char*)d_ws;
    auto alloc = [&](size_t bytes) {
        void* r = (void*)p;
        p += (bytes + 255) & ~(size_t)255;
        return r;
    };
    float* mf    = (float*)alloc((size_t)TM_ * 4);
    float* dinv  = (float*)alloc((size_t)TM_ * 4);
    int*   ecnt  = (int*)alloc((size_t)TM_ * 4);
    int*   edges = (int*)alloc((size_t)TM_ * ECAP * 4);   // aliased by lo later
    f16*   bufC  = (f16*)alloc((size_t)TM_ * H_ * 2);     // Y1, then Y2
    f16*   bufD  = (f16*)alloc((size_t)TM_ * H_ * 2);     // h1, then ph
    f16*   xg    = (f16*)alloc((size_t)TM_ * G_ * 2);
    f16*   Y1 = bufC, *Y2 = bufC;
    f16*   h1 = bufD, *ph = bufD;
    f16*   lo = (f16*)edges;    // edges dead after k5

    hipLaunchKernelGGL(k0_mask, dim3(40), dim3(1024), 0, stream, ego, mf, ecnt);
    hipLaunchKernelGGL(k1_scan, dim3(8, 20, 10), dim3(256), 0, stream,
                       adjacency, mf, ecnt, edges);
    hipLaunchKernelGGL(k2_y1, dim3(20000), dim3(256), 0, stream,
                       positions, W1, mf, ecnt, dinv, Y1);
    hipLaunchKernelGGL(k3_agg1, dim3(40000), dim3(64), 0, stream,
                       Y1, dinv, ecnt, edges, b1, h1);
    hipLaunchKernelGGL(kgemm_mfma, dim3(625, 2), dim3(256), 0, stream,
                       h1, W2, 0, 128, 0, dinv, (const float*)nullptr,
                       (const float*)nullptr, Y2);
    hipLaunchKernelGGL(k5_agg2, dim3(40000), dim3(64), 0, stream,
                       Y2, dinv, mf, ecnt, edges, b2, ph);
    hipLaunchKernelGGL(kgemm_mfma, dim3(625, 8), dim3(256), 0, stream,
                       ph, W_ih, 1, 512, 1, dinv, b_ih, b_hh, xg);
    hipLaunchKernelGGL(k7_lstm, dim3(20), dim3(512), 0, stream, W_hh, xg, lo);
    hipLaunchKernelGGL(k8_fc, dim3(512), dim3(256), 0, stream,
                       lo, fc1w, fc1b, fc2w, fc2b, out);
}

// Round 9
// 1637.339 us; speedup vs baseline: 1.0848x; 1.0848x over previous
//
#include <hip/hip_runtime.h>
#include <hip/hip_bf16.h>

#define T_   20
#define B_   4
#define NN_  500
#define M_   2000
#define TM_  40000   // T_*M_
#define H_   128
#define G_   512     // 4*H_
#define H2_  64
#define OUT_ 32
#define ECAP 64
#define TG_  (T_ * G_)

typedef unsigned short ushort_t;
typedef unsigned int   uint_t;
typedef _Float16       f16;
typedef f16 f16x2 __attribute__((ext_vector_type(2)));
typedef f16 f16x8 __attribute__((ext_vector_type(8)));
typedef float f32x4 __attribute__((ext_vector_type(4)));

#if defined(__has_builtin)
#  if __has_builtin(__builtin_amdgcn_fdot2)
#    define HAVE_FDOT2 1
#  endif
#endif

__device__ inline float fdot2_(f16x2 a, f16x2 b, float c) {
#ifdef HAVE_FDOT2
    return __builtin_amdgcn_fdot2(a, b, c, false);
#else
    return c + (float)a.x * (float)b.x + (float)a.y * (float)b.y;
#endif
}

__device__ inline float fast_sig(float x) {
    float e = __builtin_amdgcn_exp2f(x * -1.4426950408889634f);
    return __builtin_amdgcn_rcpf(1.f + e);
}
__device__ inline float fast_tanh(float x) {
    float e = __builtin_amdgcn_exp2f(x * 2.8853900817779268f);
    return 1.f - 2.f * __builtin_amdgcn_rcpf(e + 1.f);
}

// raw barrier: no compiler-inserted s_waitcnt vmcnt(0) drain.
// LDS pipe is in-order per CU (validated R3-R8: correct results).
#define BARRAW() asm volatile("s_barrier" ::: "memory")

// quad butterfly add via DPP (VALU pipe, no DS ops). Validated R8.
// 0xB1 = quad_perm [1,0,3,2] (xor1), 0x4E = quad_perm [2,3,0,1] (xor2).
#define DPPADD(v, ctrl)                                                       \
    do {                                                                      \
        int nb_ = __builtin_amdgcn_update_dpp(                                \
            0, __builtin_bit_cast(int, v), (ctrl), 0xF, 0xF, true);           \
        v += __builtin_bit_cast(float, nb_);                                  \
    } while (0)

// ---- K0: detect ego dtype + build mask[t][i] + zero ecnt ---------------
__global__ __launch_bounds__(1024) void k0_mask(const void* __restrict__ ego,
                                                float* __restrict__ mf,
                                                int* __restrict__ ecnt) {
    __shared__ int fl[3];
    int tid = threadIdx.x;
    if (tid < 3) fl[tid] = 0;
    __syncthreads();
    const uint_t* dw = (const uint_t*)ego;
    int a = 0, b = 0, c = 0;
    for (int i = tid; i < 2500; i += 1024) {   // 10 KB <= any dtype's size
        uint_t v = dw[i];
        bool isf32  = (v == 0x3F800000u);
        bool isbf16 = (v == 0x00003F80u) || (v == 0x3F803F80u);
        if (isf32)  a = 1;
        if (isbf16) b = 1;
        if (v > 1u && !isf32 && !isbf16) c = 1;
    }
    if (a) fl[0] = 1;
    if (b) fl[1] = 1;
    if (c) fl[2] = 1;
    __syncthreads();
    int mode;                       // 0=int32, 1=uint8, 2=f32, 3=bf16
    if (fl[1])      mode = 3;
    else if (fl[0]) mode = 2;
    else if (fl[2]) mode = 1;
    else            mode = 0;
    int e = blockIdx.x * 1024 + tid;
    if (e >= TM_) return;
    ecnt[e] = 0;
    int t = e / M_, i = e % M_;
    int bb = i / NN_, n = i % NN_;
    int src = (bb * T_ + t) * NN_ + n;
    bool on;
    if (mode == 0)      on = ((const int*)ego)[src] != 0;
    else if (mode == 1) on = ((const unsigned char*)ego)[src] != 0;
    else if (mode == 2) on = ((const float*)ego)[src] != 0.f;
    else                on = ((const ushort_t*)ego)[src] != 0;
    mf[e] = on ? 1.f : 0.f;
}

// ---- K1: strip-parallel adjacency scan, atomic slot alloc --------------
#define JSTRIP 200
__global__ void k1_scan(const float* __restrict__ adj, const float* __restrict__ mf,
                        int* __restrict__ ecnt, int* __restrict__ edges) {
    __shared__ float ms[JSTRIP];
    int t = blockIdx.y, j0 = blockIdx.z * JSTRIP;
    int i = blockIdx.x * 256 + threadIdx.x;
    for (int idx = threadIdx.x; idx < JSTRIP; idx += 256)
        ms[idx] = mf[t * M_ + j0 + idx];
    __syncthreads();
    if (i >= M_) return;
    if (mf[t * M_ + i] == 0.f) return;          // masked column: no edges
    const float* ap = adj + (size_t)t * M_ * M_ + (size_t)j0 * M_ + i;
    int r = t * M_ + i;
    int* ep = edges + (size_t)r * ECAP;
#pragma unroll 8
    for (int jj = 0; jj < JSTRIP; ++jj) {
        float av = ap[(size_t)jj * M_];
        if (av != 0.f && ms[jj] != 0.f) {
            int pos = atomicAdd(&ecnt[r], 1);
            if (pos < ECAP) ep[pos] = j0 + jj;
        }
    }
}

// ---- K2: dinv from ecnt/mf; Y1 = dinv * (x @ W1) -----------------------
__global__ void k2_y1(const float* __restrict__ pos, const float* __restrict__ W1,
                      const float* __restrict__ mf, const int* __restrict__ ecnt,
                      float* __restrict__ dinv, f16* __restrict__ Y1) {
    int gid = blockIdx.x * 256 + threadIdx.x;    // over TM_*H_
    int r = gid >> 7, h = gid & 127;
    if (r >= TM_) return;
    float mr = mf[r];
    int cnt = ecnt[r];
    float dv = (mr != 0.f) ? __frsqrt_rn((float)(cnt + 1)) : 0.f;
    if (h == 0) dinv[r] = dv;
    float2 xy = ((const float2*)pos)[r];
    float v = xy.x * W1[h] + xy.y * W1[H_ + h];
    Y1[gid] = (f16)(dv * v);
}

// ---- K3: h1 = relu(dinv*(sum_edges Y1 + Y1_self) + b1), f16x2 lanes ----
__global__ __launch_bounds__(64) void k3_agg1(const f16* __restrict__ Y1,
        const float* __restrict__ dinv, const int* __restrict__ ecnt,
        const int* __restrict__ edges, const float* __restrict__ b1,
        f16* __restrict__ h1) {
    int r = blockIdx.x, q = threadIdx.x;   // q: h-pair index 0..63
    int t = r / M_, base = t * M_;
    const uint_t* Yu = (const uint_t*)Y1;
    f16x2 sp = __builtin_bit_cast(f16x2, Yu[(size_t)r * 64 + q]);
    float a0 = (float)sp.x, a1 = (float)sp.y;
    int ec = ecnt[r]; if (ec > ECAP) ec = ECAP;
    const int4* ep4 = (const int4*)(edges + (size_t)r * ECAP);
    for (int e = 0; e < ec; e += 4) {
        int4 ix = ep4[e >> 2];
        int j1 = (e + 1 < ec) ? ix.y : ix.x;
        int j2 = (e + 2 < ec) ? ix.z : ix.x;
        int j3 = (e + 3 < ec) ? ix.w : ix.x;
        uint_t u0 = Yu[(size_t)(base + ix.x) * 64 + q];
        uint_t u1 = Yu[(size_t)(base + j1) * 64 + q];
        uint_t u2 = Yu[(size_t)(base + j2) * 64 + q];
        uint_t u3 = Yu[(size_t)(base + j3) * 64 + q];
        f16x2 p0 = __builtin_bit_cast(f16x2, u0);
        a0 += (float)p0.x; a1 += (float)p0.y;
        if (e + 1 < ec) { f16x2 p = __builtin_bit_cast(f16x2, u1); a0 += (float)p.x; a1 += (float)p.y; }
        if (e + 2 < ec) { f16x2 p = __builtin_bit_cast(f16x2, u2); a0 += (float)p.x; a1 += (float)p.y; }
        if (e + 3 < ec) { f16x2 p = __builtin_bit_cast(f16x2, u3); a0 += (float)p.x; a1 += (float)p.y; }
    }
    float dv = dinv[r];
    float o0 = dv * a0 + b1[2 * q];
    float o1 = dv * a1 + b1[2 * q + 1];
    f16x2 op; op.x = (f16)fmaxf(o0, 0.f); op.y = (f16)fmaxf(o1, 0.f);
    ((uint_t*)h1)[(size_t)r * 64 + q] = __builtin_bit_cast(uint_t, op);
}

// ---- K5: placeholder = (dinv*(sum Y2 + Y2_self) + b2) * m --------------
__global__ __launch_bounds__(64) void k5_agg2(const f16* __restrict__ Y2,
        const float* __restrict__ dinv, const float* __restrict__ mf,
        const int* __restrict__ ecnt, const int* __restrict__ edges,
        const float* __restrict__ b2, f16* __restrict__ ph) {
    int r = blockIdx.x, q = threadIdx.x;
    int t = r / M_, base = t * M_;
    const uint_t* Yu = (const uint_t*)Y2;
    f16x2 sp = __builtin_bit_cast(f16x2, Yu[(size_t)r * 64 + q]);
    float a0 = (float)sp.x, a1 = (float)sp.y;
    int ec = ecnt[r]; if (ec > ECAP) ec = ECAP;
    const int4* ep4 = (const int4*)(edges + (size_t)r * ECAP);
    for (int e = 0; e < ec; e += 4) {
        int4 ix = ep4[e >> 2];
        int j1 = (e + 1 < ec) ? ix.y : ix.x;
        int j2 = (e + 2 < ec) ? ix.z : ix.x;
        int j3 = (e + 3 < ec) ? ix.w : ix.x;
        uint_t u0 = Yu[(size_t)(base + ix.x) * 64 + q];
        uint_t u1 = Yu[(size_t)(base + j1) * 64 + q];
        uint_t u2 = Yu[(size_t)(base + j2) * 64 + q];
        uint_t u3 = Yu[(size_t)(base + j3) * 64 + q];
        f16x2 p0 = __builtin_bit_cast(f16x2, u0);
        a0 += (float)p0.x; a1 += (float)p0.y;
        if (e + 1 < ec) { f16x2 p = __builtin_bit_cast(f16x2, u1); a0 += (float)p.x; a1 += (float)p.y; }
        if (e + 2 < ec) { f16x2 p = __builtin_bit_cast(f16x2, u2); a0 += (float)p.x; a1 += (float)p.y; }
        if (e + 3 < ec) { f16x2 p = __builtin_bit_cast(f16x2, u3); a0 += (float)p.x; a1 += (float)p.y; }
    }
    float dv = dinv[r], mr = mf[r];
    f16x2 op;
    op.x = (f16)((dv * a0 + b2[2 * q]) * mr);
    op.y = (f16)((dv * a1 + b2[2 * q + 1]) * mr);
    ((uint_t*)ph)[(size_t)r * 64 + q] = __builtin_bit_cast(uint_t, op);
}

// ---- MFMA GEMM: [TM_ x 128] f16 @ [128 x Ntot] -> f16 ------------------
// mode=1 stores xg GATE-INTERLEAVED: slot (n&127)*4 + (n>>7).
#define ALD 136   // padded LDS leading dim in f16
__global__ __launch_bounds__(256) void kgemm_mfma(const f16* __restrict__ A,
        const float* __restrict__ Bw, int bTrans, int Ntot, int mode,
        const float* __restrict__ dinv, const float* __restrict__ ba,
        const float* __restrict__ bb, f16* __restrict__ Out) {
    __shared__ f16 As[64 * ALD];
    __shared__ f16 Bs[64 * ALD];
    int m0 = blockIdx.x * 64;
    int n0 = blockIdx.y * 64;
    int tid = threadIdx.x;
#pragma unroll
    for (int u = 0; u < 4; ++u) {
        int idx = u * 256 + tid;
        int row = idx >> 4, seg = idx & 15;
        *(f16x8*)&As[row * ALD + seg * 8] =
            *(const f16x8*)(A + (size_t)(m0 + row) * H_ + seg * 8);
    }
    if (bTrans) {   // Bw [Ntot][128]
#pragma unroll
        for (int u = 0; u < 16; ++u) {
            int idx = u * 256 + tid;
            int n = idx >> 6, k2 = (idx & 63) * 2;
            float2 v = *(const float2*)(Bw + (size_t)(n0 + n) * H_ + k2);
            f16x2 pk; pk.x = (f16)v.x; pk.y = (f16)v.y;
            *(uint_t*)&Bs[n * ALD + k2] = __builtin_bit_cast(uint_t, pk);
        }
    } else {        // Bw [128][Ntot]
#pragma unroll
        for (int u = 0; u < 16; ++u) {
            int idx = u * 256 + tid;
            int n = idx >> 6, k2 = (idx & 63) * 2;
            f16x2 pk;
            pk.x = (f16)Bw[(size_t)k2 * Ntot + n0 + n];
            pk.y = (f16)Bw[(size_t)(k2 + 1) * Ntot + n0 + n];
            *(uint_t*)&Bs[n * ALD + k2] = __builtin_bit_cast(uint_t, pk);
        }
    }
    __syncthreads();
    int w = tid >> 6, lane = tid & 63;
    int col = lane & 15, quad = lane >> 4;
    f32x4 acc[4] = {};
#pragma unroll
    for (int kk = 0; kk < 4; ++kk) {
        f16x8 af = *(const f16x8*)&As[(w * 16 + col) * ALD + kk * 32 + quad * 8];
#pragma unroll
        for (int nt = 0; nt < 4; ++nt) {
            f16x8 bf = *(const f16x8*)&Bs[(nt * 16 + col) * ALD + kk * 32 + quad * 8];
            acc[nt] = __builtin_amdgcn_mfma_f32_16x16x32_f16(af, bf, acc[nt], 0, 0, 0);
        }
    }
    if (mode == 0) {
        float dv[4];
#pragma unroll
        for (int reg = 0; reg < 4; ++reg)
            dv[reg] = dinv[m0 + w * 16 + quad * 4 + reg];
#pragma unroll
        for (int nt = 0; nt < 4; ++nt) {
            int n = n0 + nt * 16 + col;
#pragma unroll
            for (int reg = 0; reg < 4; ++reg) {
                int r = m0 + w * 16 + quad * 4 + reg;
                Out[(size_t)r * Ntot + n] = (f16)(dv[reg] * acc[nt][reg]);
            }
        }
    } else {
#pragma unroll
        for (int nt = 0; nt < 4; ++nt) {
            int n = n0 + nt * 16 + col;
            float bias = ba[n] + bb[n];
            int pos = (n & 127) * 4 + (n >> 7);   // gate-interleaved slot
#pragma unroll
            for (int reg = 0; reg < 4; ++reg) {
                int r = m0 + w * 16 + quad * 4 + reg;
                int t = r / M_, s = r % M_;
                Out[((size_t)s * T_ + t) * G_ + pos] = (f16)(acc[nt][reg] + bias);
            }
        }
    }
}

// ---- K7: 20 LSTM chains; VALU dot2, FORCED register residency ----------
// waves_per_eu(1,1) clamps occupancy (launch_bounds' 2nd arg is only a
// MINIMUM — R3/R4/R8 showed the compiler targeting ~7 waves/EU, capping
// VGPRs at ~72 and rematerializing the weight arrays every step).
// tid = r*4+c: lane owns rows r+64j (j=0..7: all 4 gates for h=r and
// h=r+64) at k-chunk c (32 elems) -> 128 fdot2 in 8 independent chains,
// 128 weight VGPRs. LDS: 4 ds_read_b128/lane = 16 inst/CU/step. Quad DPP
// butterfly -> all 8 sums everywhere; c<2 updates h=r, c>=2 h=r+64.
__global__ __launch_bounds__(256, 1)
__attribute__((amdgpu_waves_per_eu(1, 1)))
void k7_lstm(const float* __restrict__ Whh,
             const f16* __restrict__ xg, f16* __restrict__ lo) {
    __shared__ ushort_t hb2[2][H_];   // double-buffered h (128 f16 each)
    int t = blockIdx.x, tid = threadIdx.x;
    int r = tid >> 2, c = tid & 3;
    // wv[j][d] = W_hh[(r + 64j)][c*32 + 2d .. +1]  (row = gate*128 + h)
    f16x2 wv[8][16];
#pragma unroll
    for (int j = 0; j < 8; ++j) {
        const float* wr = Whh + (size_t)(r + 64 * j) * H_ + c * 32;
#pragma unroll
        for (int d = 0; d < 16; ++d) {
            f16x2 p; p.x = (f16)wr[2 * d]; p.y = (f16)wr[2 * d + 1];
            wv[j][d] = p;
        }
    }
    if (tid < H_) hb2[0][tid] = 0;
    int hsel = (c < 2) ? r : r + 64;
    bool wr0 = (c & 1) == 0;
    float cst = 0.f;
    const uint_t* xbase = (const uint_t*)xg;   // gate-interleaved
    uint2 xa[4], xb[4];
#pragma unroll
    for (int k = 0; k < 4; ++k)
        xa[k] = *(const uint2*)(xbase + ((size_t)k * T_ + t) * 256 + hsel * 2);
    __syncthreads();

#define LSTM_STEP(S, XV)                                                      \
    do {                                                                      \
        const ushort_t* hp = &hb2[(S) & 1][c * 32];                           \
        uint4 u0 = ((const uint4*)hp)[0];                                     \
        uint4 u1 = ((const uint4*)hp)[1];                                     \
        uint4 u2 = ((const uint4*)hp)[2];                                     \
        uint4 u3 = ((const uint4*)hp)[3];                                     \
        uint_t hu[16] = {u0.x, u0.y, u0.z, u0.w, u1.x, u1.y, u1.z, u1.w,      \
                         u2.x, u2.y, u2.z, u2.w, u3.x, u3.y, u3.z, u3.w};     \
        float a0 = 0.f, a1 = 0.f, a2 = 0.f, a3 = 0.f;                         \
        float a4 = 0.f, a5 = 0.f, a6 = 0.f, a7 = 0.f;                         \
        _Pragma("unroll")                                                     \
        for (int d = 0; d < 16; ++d) {                                        \
            f16x2 e = __builtin_bit_cast(f16x2, hu[d]);                       \
            a0 = fdot2_(wv[0][d], e, a0);                                     \
            a1 = fdot2_(wv[1][d], e, a1);                                     \
            a2 = fdot2_(wv[2][d], e, a2);                                     \
            a3 = fdot2_(wv[3][d], e, a3);                                     \
            a4 = fdot2_(wv[4][d], e, a4);                                     \
            a5 = fdot2_(wv[5][d], e, a5);                                     \
            a6 = fdot2_(wv[6][d], e, a6);                                     \
            a7 = fdot2_(wv[7][d], e, a7);                                     \
        }                                                                     \
        DPPADD(a0, 0xB1); DPPADD(a0, 0x4E);                                   \
        DPPADD(a1, 0xB1); DPPADD(a1, 0x4E);                                   \
        DPPADD(a2, 0xB1); DPPADD(a2, 0x4E);                                   \
        DPPADD(a3, 0xB1); DPPADD(a3, 0x4E);                                   \
        DPPADD(a4, 0xB1); DPPADD(a4, 0x4E);                                   \
        DPPADD(a5, 0xB1); DPPADD(a5, 0x4E);                                   \
        DPPADD(a6, 0xB1); DPPADD(a6, 0x4E);                                   \
        DPPADD(a7, 0xB1); DPPADD(a7, 0x4E);                                   \
        float vi = (c < 2) ? a0 : a1;                                         \
        float vf = (c < 2) ? a2 : a3;                                         \
        float vg = (c < 2) ? a4 : a5;                                         \
        float vo = (c < 2) ? a6 : a7;                                         \
        f16x2 xlo = __builtin_bit_cast(f16x2, (XV).x);                        \
        f16x2 xhi = __builtin_bit_cast(f16x2, (XV).y);                        \
        float gi = fast_sig(vi + (float)xlo.x);                               \
        float gf = fast_sig(vf + (float)xlo.y);                               \
        float gg = fast_tanh(vg + (float)xhi.x);                              \
        float go = fast_sig(vo + (float)xhi.y);                               \
        cst = gf * cst + gi * gg;                                             \
        float hv_ = go * fast_tanh(cst);                                      \
        f16 hh = (f16)hv_;                                                    \
        if (wr0) {                                                            \
            hb2[((S) & 1) ^ 1][hsel] = __builtin_bit_cast(ushort_t, hh);      \
            lo[((size_t)(S) * T_ + t) * H_ + hsel] = hh;                      \
        }                                                                     \
        BARRAW();                                                             \
    } while (0)

    for (int c2 = 0; c2 < 250; ++c2) {
        int s0 = c2 * 8;
#pragma unroll
        for (int k = 0; k < 4; ++k)
            xb[k] = *(const uint2*)(xbase + ((size_t)(s0 + 4 + k) * T_ + t) * 256 + hsel * 2);
#pragma unroll
        for (int k = 0; k < 4; ++k) LSTM_STEP(s0 + k, xa[k]);
        int nbs = (s0 + 8 <= M_ - 4) ? s0 + 8 : M_ - 4;
#pragma unroll
        for (int k = 0; k < 4; ++k)
            xa[k] = *(const uint2*)(xbase + ((size_t)(nbs + k) * T_ + t) * 256 + hsel * 2);
#pragma unroll
        for (int k = 0; k < 4; ++k) LSTM_STEP(s0 + 4 + k, xb[k]);
    }
#undef LSTM_STEP
}

// ---- K8: fc1(relu)+fc2; weights in VGPRs; stream 4 rows/iter -----------
__global__ __launch_bounds__(256) void k8_fc(const f16* __restrict__ lo,
        const float* __restrict__ w1, const float* __restrict__ fb1,
        const float* __restrict__ w2, const float* __restrict__ fb2,
        float* __restrict__ out) {
    __shared__ uint_t hl[4][H_ / 2];   // 4 rows x 128 f16
    __shared__ float o1f[4][H2_];
    int tid = threadIdx.x;
    int o = tid & 63, rr = tid >> 6;
    f16x2 w1c[64];
#pragma unroll
    for (int d = 0; d < 64; ++d) {
        f16x2 p;
        p.x = (f16)w1[(2 * d) * H2_ + o];
        p.y = (f16)w1[(2 * d + 1) * H2_ + o];
        w1c[d] = p;
    }
    int o2 = o & 31;
    float w2f[64];
#pragma unroll
    for (int d = 0; d < 64; ++d) w2f[d] = w2[d * OUT_ + o2];
    float fb1v = fb1[o], fb2v = fb2[o2];

    for (int r0 = blockIdx.x * 4; r0 < TM_; r0 += 512 * 4) {
        {
            int row = tid >> 6, qq = tid & 63;
            hl[row][qq] = ((const uint_t*)lo)[(size_t)(r0 + row) * 64 + qq];
        }
        __syncthreads();
        float acc = fb1v;
        const uint4* hb = (const uint4*)&hl[rr][0];
#pragma unroll
        for (int d = 0; d < 16; ++d) {
            uint4 hv = hb[d];
            acc = fdot2_(w1c[4 * d + 0], __builtin_bit_cast(f16x2, hv.x), acc);
            acc = fdot2_(w1c[4 * d + 1], __builtin_bit_cast(f16x2, hv.y), acc);
            acc = fdot2_(w1c[4 * d + 2], __builtin_bit_cast(f16x2, hv.z), acc);
            acc = fdot2_(w1c[4 * d + 3], __builtin_bit_cast(f16x2, hv.w), acc);
        }
        o1f[rr][o] = fmaxf(acc, 0.f);
        __syncthreads();
        if (o < OUT_) {
            float a2 = fb2v;
            const float4* ob = (const float4*)&o1f[rr][0];
#pragma unroll
            for (int d = 0; d < 16; ++d) {
                float4 v = ob[d];
                a2 += v.x * w2f[4 * d + 0] + v.y * w2f[4 * d + 1]
                    + v.z * w2f[4 * d + 2] + v.w * w2f[4 * d + 3];
            }
            out[(size_t)(r0 + rr) * OUT_ + o] = a2;
        }
        __syncthreads();
    }
}

extern "C" void kernel_launch(void* const* d_in, const int* in_sizes, int n_in,
                              void* d_out, int out_size, void* d_ws, size_t ws_size,
                              hipStream_t stream) {
    const float* positions = (const float*)d_in[0];
    const float* adjacency = (const float*)d_in[1];
    const void*  ego       = d_in[2];
    const float* W1   = (const float*)d_in[3];
    const float* b1   = (const float*)d_in[4];
    const float* W2   = (const float*)d_in[5];
    const float* b2   = (const float*)d_in[6];
    const float* W_ih = (const float*)d_in[7];
    const float* W_hh = (const float*)d_in[8];
    const float* b_ih = (const float*)d_in[9];
    const float* b_hh = (const float*)d_in[10];
    const float* fc1w = (const float*)d_in[11];
    const float* fc1b = (const float*)d_in[12];
    const float* fc2w = (const float*)d_in[13];
    const float* fc2b = (const float*)d_in[14];
    float* out = (float*)d_out;

    char* p = (char*)d_ws;
    auto alloc = [&](size_t bytes) {
        void* r = (void*)p;
        p += (bytes + 255) & ~(size_t)255;
        return r;
    };
    float* mf    = (float*)alloc((size_t)TM_ * 4);
    float* dinv  = (float*)alloc((size_t)TM_ * 4);
    int*   ecnt  = (int*)alloc((size_t)TM_ * 4);
    int*   edges = (int*)alloc((size_t)TM_ * ECAP * 4);   // aliased by lo later
    f16*   bufC  = (f16*)alloc((size_t)TM_ * H_ * 2);     // Y1, then Y2
    f16*   bufD  = (f16*)alloc((size_t)TM_ * H_ * 2);     // h1, then ph
    f16*   xg    = (f16*)alloc((size_t)TM_ * G_ * 2);
    f16*   Y1 = bufC, *Y2 = bufC;
    f16*   h1 = bufD, *ph = bufD;
    f16*   lo = (f16*)edges;    // edges dead after k5

    hipLaunchKernelGGL(k0_mask, dim3(40), dim3(1024), 0, stream, ego, mf, ecnt);
    hipLaunchKernelGGL(k1_scan, dim3(8, 20, 10), dim3(256), 0, stream,
                       adjacency, mf, ecnt, edges);
    hipLaunchKernelGGL(k2_y1, dim3(20000), dim3(256), 0, stream,
                       positions, W1, mf, ecnt, dinv, Y1);
    hipLaunchKernelGGL(k3_agg1, dim3(40000), dim3(64), 0, stream,
                       Y1, dinv, ecnt, edges, b1, h1);
    hipLaunchKernelGGL(kgemm_mfma, dim3(625, 2), dim3(256), 0, stream,
                       h1, W2, 0, 128, 0, dinv, (const float*)nullptr,
                       (const float*)nullptr, Y2);
    hipLaunchKernelGGL(k5_agg2, dim3(40000), dim3(64), 0, stream,
                       Y2, dinv, mf, ecnt, edges, b2, ph);
    hipLaunchKernelGGL(kgemm_mfma, dim3(625, 8), dim3(256), 0, stream,
                       ph, W_ih, 1, 512, 1, dinv, b_ih, b_hh, xg);
    hipLaunchKernelGGL(k7_lstm, dim3(20), dim3(256), 0, stream, W_hh, xg, lo);
    hipLaunchKernelGGL(k8_fc, dim3(512), dim3(256), 0, stream,
                       lo, fc1w, fc1b, fc2w, fc2b, out);
}